// Round 4
// baseline (498.508 us; speedup 1.0000x reference)
//
#include <hip/hip_runtime.h>
#include <hip/hip_bf16.h>
#include <math.h>

// RaffelAttention round 4.
// B=2 L=2048 D=1024 H=16 HD=64.  Q' = [cq|pq]*0.125*log2e, K' = [ck|pk], V = ck.
// attn: swapped QK^T (S^T, q in lane dim) -> scalar lsum, in-register P via
// pack+shfl_xor(32), vectorized Ps staging + 256B P stores.
// pass1: 3-buffer rotation, counted vmcnt(4). proj/out: m97-style gload_lds
// with XOR-swizzled source + swizzled ds_read_b128.

#define Bc 2
#define Lc 2048
#define Dc 1024
#define Hc 16
#define Mc (Bc*Lc)
#define NT 32

typedef __attribute__((ext_vector_type(8))) __bf16 bf16x8;
typedef __attribute__((ext_vector_type(4))) float f32x4;
typedef __attribute__((ext_vector_type(16))) float f32x16;

union U4 { unsigned u[4]; bf16x8 v; };

__device__ __forceinline__ void gl_lds16(const void* g, void* l) {
    __builtin_amdgcn_global_load_lds(
        (const __attribute__((address_space(1))) void*)g,
        (__attribute__((address_space(3))) void*)l, 16, 0, 0);
}
__device__ __forceinline__ unsigned pkbf(float a, float b) {
    unsigned short ua = __builtin_bit_cast(unsigned short, (__bf16)a);
    unsigned short ub = __builtin_bit_cast(unsigned short, (__bf16)b);
    return (unsigned)ua | ((unsigned)ub << 16);
}
__device__ __forceinline__ float lo2f(unsigned u){ return __builtin_bit_cast(float, u << 16); }
__device__ __forceinline__ float hi2f(unsigned u){ return __builtin_bit_cast(float, u & 0xffff0000u); }

#define WAIT_VM0 asm volatile("s_waitcnt vmcnt(0)" ::: "memory")
#define WAIT_VM4 asm volatile("s_waitcnt vmcnt(4)" ::: "memory")
#define WAIT_VM8 asm volatile("s_waitcnt vmcnt(8)" ::: "memory")
#define WAIT_LG0 asm volatile("s_waitcnt lgkmcnt(0)" ::: "memory")
#define BARRIER do { __builtin_amdgcn_sched_barrier(0); __builtin_amdgcn_s_barrier(); __builtin_amdgcn_sched_barrier(0); } while (0)

// ---------------------------------------------------------------------------
// prep: transpose weights to bf16 [n][k].  z=0..3 -> Wt[z]; z=4 -> Woh/Wol.
// ---------------------------------------------------------------------------
__global__ __launch_bounds__(256) void prep_kernel(
    const float* __restrict__ Wcq, const float* __restrict__ Wck,
    const float* __restrict__ Wpq, const float* __restrict__ Wpk,
    const float* __restrict__ Wo,
    __bf16* __restrict__ Wt, __bf16* __restrict__ Woh, __bf16* __restrict__ Wol)
{
    const int z = blockIdx.z;
    const float* W = (z==0)?Wcq:(z==1)?Wck:(z==2)?Wpq:(z==3)?Wpk:Wo;
    const int t = threadIdx.x;
    const int n  = blockIdx.x*64 + (t & 63);
    const int k0 = blockIdx.y*128 + (t >> 6)*32;
    float v[32];
    #pragma unroll
    for (int j = 0; j < 32; ++j) v[j] = W[(size_t)(k0+j)*Dc + n];
    if (z < 4) {
        __bf16* dst = Wt + (size_t)z*Dc*Dc + (size_t)n*Dc + k0;
        #pragma unroll
        for (int c = 0; c < 4; ++c) {
            bf16x8 o;
            #pragma unroll
            for (int j = 0; j < 8; ++j) o[j] = (__bf16)v[c*8+j];
            *(bf16x8*)(dst + c*8) = o;
        }
    } else {
        __bf16* dh = Woh + (size_t)n*Dc + k0;
        __bf16* dl = Wol + (size_t)n*Dc + k0;
        #pragma unroll
        for (int c = 0; c < 4; ++c) {
            bf16x8 oh, ol;
            #pragma unroll
            for (int j = 0; j < 8; ++j) {
                float x = v[c*8+j];
                __bf16 hi = (__bf16)x;
                oh[j] = hi; ol[j] = (__bf16)(x - (float)hi);
            }
            *(bf16x8*)(dh + c*8) = oh;
            *(bf16x8*)(dl + c*8) = ol;
        }
    }
}

// ---------------------------------------------------------------------------
// proj: X(fp32) @ Wt[z](bf16,[n][k]) -> Q'/K' bf16 [B,H,L,128] halves.
// m97-style: gload_lds staging (A stays f32 in LDS, cvt on read), XOR swizzle.
// ---------------------------------------------------------------------------
__global__ __launch_bounds__(256) void proj_kernel(
    const float* __restrict__ hidden, const float* __restrict__ pos,
    const __bf16* __restrict__ Wt,
    const float* __restrict__ bcq, const float* __restrict__ bck,
    const float* __restrict__ bpq, const float* __restrict__ bpk,
    __bf16* __restrict__ Qc, __bf16* __restrict__ Kc)
{
    const int g = blockIdx.x;
    const int nblk = g >> 7, sg = g & 127, mblk = sg & 31, z = sg >> 5;
    const int m0 = mblk*128, n0 = nblk*128;
    const float* X = (z < 2) ? hidden : pos;
    const __bf16* Wz = Wt + (size_t)z*Dc*Dc;
    const float* bias = (z==0)?bcq:(z==1)?bck:(z==2)?bpq:bpk;
    __bf16* dst = (z & 1) ? Kc : Qc;
    const int half = z >> 1;
    const float scale = (z & 1) ? 1.0f : 0.18033688011112042f; // 0.125*log2e on Q

    const int t = threadIdx.x, lane = t & 63, w = t >> 6;
    const int wm = w >> 1, wn = w & 1;

    __shared__ __align__(16) float  Asf[128][32];
    __shared__ __align__(16) __bf16 Bs[128][32];

    const int arowL = lane >> 3;                       // 0..7
    const int acol  = ((lane & 7) ^ arowL) * 4;        // f32 col (src pre-swizzle)
    const int brow4 = lane >> 2;                       // 0..15
    const int bcol  = ((lane & 3) ^ (brow4 & 3)) * 8;  // bf16 col

    f32x4 acc[4][4] = {};

    for (int k0 = 0; k0 < Dc; k0 += 32) {
        #pragma unroll
        for (int i = 0; i < 4; ++i) {
            int row = 8*(4*w+i) + arowL;
            gl_lds16(X + (size_t)(m0+row)*Dc + k0 + acol, (char*)Asf + (4*w+i)*1024);
        }
        #pragma unroll
        for (int i = 0; i < 2; ++i) {
            int row = 16*(2*w+i) + brow4;
            gl_lds16(Wz + (size_t)(n0+row)*Dc + k0 + bcol, (char*)Bs + (2*w+i)*1024);
        }
        WAIT_VM0; __syncthreads();
        bf16x8 a[4], b[4];
        const int s2 = lane >> 4;
        #pragma unroll
        for (int i = 0; i < 4; ++i) {
            int R = wm*64 + i*16 + (lane&15);
            f32x4 x0 = *(const f32x4*)((const char*)&Asf[R][0] + (((2*s2  ) ^ (R&7))*16));
            f32x4 x1 = *(const f32x4*)((const char*)&Asf[R][0] + (((2*s2+1) ^ (R&7))*16));
            bf16x8 af;
            af[0]=(__bf16)x0[0]; af[1]=(__bf16)x0[1]; af[2]=(__bf16)x0[2]; af[3]=(__bf16)x0[3];
            af[4]=(__bf16)x1[0]; af[5]=(__bf16)x1[1]; af[6]=(__bf16)x1[2]; af[7]=(__bf16)x1[3];
            a[i] = af;
            int Rb = wn*64 + i*16 + (lane&15);
            b[i] = *(const bf16x8*)((const char*)&Bs[Rb][0] + ((s2 ^ (Rb&3))*16));
        }
        #pragma unroll
        for (int mi = 0; mi < 4; ++mi)
            #pragma unroll
            for (int ni = 0; ni < 4; ++ni)
                acc[mi][ni] = __builtin_amdgcn_mfma_f32_16x16x32_bf16(a[mi], b[ni], acc[mi][ni], 0, 0, 0);
        __syncthreads();
    }
    #pragma unroll
    for (int mi = 0; mi < 4; ++mi)
        #pragma unroll
        for (int ni = 0; ni < 4; ++ni)
            #pragma unroll
            for (int r = 0; r < 4; ++r) {
                int row = m0 + wm*64 + mi*16 + (lane>>4)*4 + r;
                int col = n0 + wn*64 + ni*16 + (lane&15);
                float v = (acc[mi][ni][r] + bias[col]) * scale;
                int bb = row >> 11, l = row & (Lc-1);
                int hh = col >> 6,  hd = col & 63;
                dst[(((size_t)bb*Hc + hh)*Lc + l)*128 + half*64 + hd] = (__bf16)v;
            }
}

// ---------------------------------------------------------------------------
// vt: VT[bh][d 0..63][l 0..2047] = Kc[bh][l][d]  (V = ck = first 64 dims)
// ---------------------------------------------------------------------------
__global__ __launch_bounds__(256) void vt_kernel(
    const __bf16* __restrict__ Kc, __bf16* __restrict__ VT)
{
    const int l0 = blockIdx.x * 128, hb = blockIdx.y;
    const int t = threadIdx.x, w = t >> 6, lane = t & 63;
    __shared__ __bf16 T[128][72];
    const __bf16* src = Kc + ((size_t)hb*Lc + l0)*128;
    {
        const int lr = t >> 3, cc = t & 7;
        #pragma unroll
        for (int j = 0; j < 4; ++j)
            *(bf16x8*)&T[lr + j*32][cc*8] = *(const bf16x8*)(src + (size_t)(lr + j*32)*128 + cc*8);
    }
    __syncthreads();
    {
        const int d = lane;
        __bf16* dstp = VT + ((size_t)hb*64 + d)*Lc + l0 + w*32;
        #pragma unroll
        for (int j = 0; j < 4; ++j) {
            bf16x8 o;
            #pragma unroll
            for (int i = 0; i < 8; ++i) o[i] = T[w*32 + j*8 + i][d];
            *(bf16x8*)(dstp + j*8) = o;
        }
    }
}

// ---------------------------------------------------------------------------
// attn: per (b,h,128-row q-tile). 4 waves, 32x32x16 MFMA, swapped QK^T.
// ---------------------------------------------------------------------------
__global__ __launch_bounds__(256, 2) void attn_kernel(
    const __bf16* __restrict__ Qc, const __bf16* __restrict__ Kc,
    const __bf16* __restrict__ VT, const float* __restrict__ rel_bias,
    float* __restrict__ attn, __bf16* __restrict__ ctxh)
{
    const int g = blockIdx.x;
    const int qt = g >> 5, hb = g & 31, h = hb & 15, bb = hb >> 4;
    const int q0 = qt * 128;
    const int t = threadIdx.x, lane = t & 63, w = t >> 6;
    const int ln31 = lane & 31, hi = lane >> 5;

    const __bf16* Qp = Qc + (size_t)hb * Lc * 128;
    const __bf16* Kp = Kc + (size_t)hb * Lc * 128;
    const __bf16* Vp = VT + (size_t)hb * 64 * Lc;

    // LDS union: pass1 = Ks x3 (48KB); pass2 = Ks x2 (32KB) + Vs (16KB) + Ps (18KB)
    __shared__ __align__(16) char smem[67584];
    char* const VsB = smem + 32768;
    char* const PsB = smem + 49152;

    // Q fragments (used as B operand): col = q = ln31, k = ks*16 + hi*8
    bf16x8 qa[8];
    {
        const __bf16* qrow = Qp + (size_t)(q0 + w*32 + ln31) * 128 + hi*8;
        #pragma unroll
        for (int ks = 0; ks < 8; ++ks) qa[ks] = *(const bf16x8*)(qrow + ks*16);
    }

    // staging source offsets (inverse-swizzled; LDS dest linear)
    int kof[4];
    #pragma unroll
    for (int c = 0; c < 4; ++c) {
        int rl = c*4 + (lane >> 4);
        int rr = w*16 + rl;
        kof[c] = rr*128 + (((lane & 15) ^ rl) * 8);
    }
    int vof[2];
    #pragma unroll
    for (int c = 0; c < 2; ++c) {
        int dl = lane >> 3;
        int dd = w*16 + c*8 + dl;
        vof[c] = dd*2048 + (((lane & 7) ^ dl) * 8);
    }
    int kR[8];
    #pragma unroll
    for (int ks = 0; ks < 8; ++ks) kR[ks] = ((ks*2 + hi) ^ (lane & 15)) * 8;
    int vR[4];
    #pragma unroll
    for (int ks = 0; ks < 4; ++ks) vR[ks] = ((ks*2 + hi) ^ (lane & 7)) * 8;

    #define STAGE_K(B, KT) do { \
        const __bf16* kb_ = Kp + (size_t)(KT)*8192; \
        gl_lds16(kb_ + kof[0], smem + ((B)*64 + w*16 +  0)*256); \
        gl_lds16(kb_ + kof[1], smem + ((B)*64 + w*16 +  4)*256); \
        gl_lds16(kb_ + kof[2], smem + ((B)*64 + w*16 +  8)*256); \
        gl_lds16(kb_ + kof[3], smem + ((B)*64 + w*16 + 12)*256); \
    } while (0)
    #define STAGE_V(B, KT) do { \
        const __bf16* vb_ = Vp + (KT)*64; \
        gl_lds16(vb_ + vof[0], VsB + ((B)*64 + w*16 + 0)*128); \
        gl_lds16(vb_ + vof[1], VsB + ((B)*64 + w*16 + 8)*128); \
    } while (0)
    #define KB(B, ROW, KS) (*(const bf16x8*)(smem + ((B)*64 + (ROW))*256 + kR[KS]*2))
    #define VB(B, ROW, KS) (*(const bf16x8*)(VsB  + ((B)*64 + (ROW))*128 + vR[KS]*2))

    const float bc = rel_bias[h] * 0.18033688011112042f;

    // ---------------- pass 1: per-lane scalar sumexp (swapped: q = lane)
    float lsum = 0.f;
    STAGE_K(0, 0); STAGE_K(1, 1);
    for (int kt = 0; kt < NT; ++kt) {
        const int buf = kt % 3;
        if (kt == NT-1) { WAIT_VM0; } else { WAIT_VM4; }
        BARRIER;
        if (kt+2 < NT) STAGE_K((kt+2) % 3, kt+2);
        f32x16 s0 = {}, s1 = {};
        __builtin_amdgcn_s_setprio(1);
        #pragma unroll
        for (int ks = 0; ks < 8; ++ks) {
            bf16x8 kb0 = KB(buf, ln31, ks);
            bf16x8 kb1 = KB(buf, 32 + ln31, ks);
            s0 = __builtin_amdgcn_mfma_f32_32x32x16_bf16(kb0, qa[ks], s0, 0, 0, 0);
            s1 = __builtin_amdgcn_mfma_f32_32x32x16_bf16(kb1, qa[ks], s1, 0, 0, 0);
        }
        __builtin_amdgcn_s_setprio(0);
        #pragma unroll
        for (int r = 0; r < 16; ++r)
            lsum += exp2f(s0[r] + bc) + exp2f(s1[r] + bc);
    }
    lsum += __shfl_xor(lsum, 32);
    const float badd = bc - log2f(lsum);

    // ---------------- pass 2: P out + PV
    f32x16 ctx0 = {}, ctx1 = {};
    float* attn_base = attn + ((size_t)hb*Lc + q0)*Lc;
    const int qrow = w*32 + ln31;          // this lane's q row (P owner)
    const int srow = t >> 1;               // store-path q row
    const int ch   = (t & 1) * 32;         // store-path kv half

    BARRIER;                                // pass1 reads done before re-stage
    STAGE_K(0, 0); STAGE_V(0, 0);
    WAIT_VM0; BARRIER;
    int buf = 0;
    for (int kt = 0; kt < NT; ++kt, buf ^= 1) {
        if (kt+1 < NT) { STAGE_K(buf^1, kt+1); STAGE_V(buf^1, kt+1); }
        f32x16 s0 = {}, s1 = {};
        __builtin_amdgcn_s_setprio(1);
        #pragma unroll
        for (int ks = 0; ks < 8; ++ks) {
            bf16x8 kb0 = KB(buf, ln31, ks);
            bf16x8 kb1 = KB(buf, 32 + ln31, ks);
            s0 = __builtin_amdgcn_mfma_f32_32x32x16_bf16(kb0, qa[ks], s0, 0, 0, 0);
            s1 = __builtin_amdgcn_mfma_f32_32x32x16_bf16(kb1, qa[ks], s1, 0, 0, 0);
        }
        __builtin_amdgcn_s_setprio(0);
        // p = exp2(s + badd); pack pairs; exchange hi/lo kv halves
        unsigned u0[8], u1[8], r0[8], r1[8];
        #pragma unroll
        for (int gq = 0; gq < 4; ++gq) {
            u0[gq]   = pkbf(exp2f(s0[4*gq+0]+badd), exp2f(s0[4*gq+1]+badd));
            u1[gq]   = pkbf(exp2f(s0[4*gq+2]+badd), exp2f(s0[4*gq+3]+badd));
            u0[4+gq] = pkbf(exp2f(s1[4*gq+0]+badd), exp2f(s1[4*gq+1]+badd));
            u1[4+gq] = pkbf(exp2f(s1[4*gq+2]+badd), exp2f(s1[4*gq+3]+badd));
        }
        #pragma unroll
        for (int gq = 0; gq < 8; ++gq) {
            r0[gq] = __shfl_xor(u0[gq], 32);
            r1[gq] = __shfl_xor(u1[gq], 32);
        }
        // assemble PV A-fragments (kv ascending) + staged Ps writes
        bf16x8 pb[4];
        #pragma unroll
        for (int ks = 0; ks < 4; ++ks) {
            const int gq = 2*ks + hi;
            U4 u;
            u.u[0] = hi ? r0[gq] : u0[gq];
            u.u[1] = hi ? r1[gq] : u1[gq];
            u.u[2] = hi ? u0[gq] : r0[gq];
            u.u[3] = hi ? u1[gq] : r1[gq];
            pb[ks] = u.v;
            *(bf16x8*)(PsB + qrow*144 + ((gq ^ (qrow & 7))*16)) = u.v;
        }
        __builtin_amdgcn_s_setprio(1);
        #pragma unroll
        for (int ks = 0; ks < 4; ++ks) {
            bf16x8 v0 = VB(buf, ln31, ks);
            bf16x8 v1 = VB(buf, 32 + ln31, ks);
            ctx0 = __builtin_amdgcn_mfma_f32_32x32x16_bf16(pb[ks], v0, ctx0, 0, 0, 0);
            ctx1 = __builtin_amdgcn_mfma_f32_32x32x16_bf16(pb[ks], v1, ctx1, 0, 0, 0);
        }
        __builtin_amdgcn_s_setprio(0);
        WAIT_LG0; BARRIER;                 // Ps visible
        {   // coalesced P store: thread -> 32 f32 (row srow, cols ch..ch+31)
            const char* rowp = PsB + srow*144;
            float* gdst = attn_base + (size_t)srow*Lc + kt*64 + ch;
            #pragma unroll
            for (int j = 0; j < 4; ++j) {
                const int lb = (ch >> 3) + j;
                U4 blk = *(const U4*)(rowp + ((lb ^ (srow & 7))*16));
                f32x4 o0, o1;
                o0[0]=lo2f(blk.u[0]); o0[1]=hi2f(blk.u[0]); o0[2]=lo2f(blk.u[1]); o0[3]=hi2f(blk.u[1]);
                o1[0]=lo2f(blk.u[2]); o1[1]=hi2f(blk.u[2]); o1[2]=lo2f(blk.u[3]); o1[3]=hi2f(blk.u[3]);
                *(f32x4*)(gdst + 8*j)     = o0;
                *(f32x4*)(gdst + 8*j + 4) = o1;
            }
        }
        if (kt+1 < NT) { WAIT_VM8; BARRIER; }   // drain next-tile loads, stores fly on
    }

    #pragma unroll
    for (int r = 0; r < 16; ++r) {
        const int R = (r&3) + 8*(r>>2) + 4*hi;
        const size_t row = (size_t)bb*Lc + q0 + w*32 + R;
        ctxh[row*Dc + h*64 + ln31]      = (__bf16)ctx0[r];
        ctxh[row*Dc + h*64 + 32 + ln31] = (__bf16)ctx1[r];
    }
    #undef STAGE_K
    #undef STAGE_V
    #undef KB
    #undef VB
}

// ---------------------------------------------------------------------------
// out: ctxh(bf16) @ Wo + bo, B split hi/lo.  m97-style gload_lds + swizzle.
// ---------------------------------------------------------------------------
__global__ __launch_bounds__(256) void out_kernel(
    const __bf16* __restrict__ ctxh, const __bf16* __restrict__ Woh,
    const __bf16* __restrict__ Wol, const float* __restrict__ bo,
    float* __restrict__ out)
{
    const int m0 = blockIdx.y * 128, n0 = blockIdx.x * 128;
    const int t = threadIdx.x, lane = t & 63, w = t >> 6;
    const int wm = w >> 1, wn = w & 1;

    __shared__ __align__(16) __bf16 As[128][32];
    __shared__ __align__(16) __bf16 Bh[128][32];
    __shared__ __align__(16) __bf16 Bl[128][32];

    const int row4 = lane >> 2;
    const int scol = ((lane & 3) ^ (row4 & 3)) * 8;

    f32x4 acc[4][4] = {};

    for (int k0 = 0; k0 < Dc; k0 += 32) {
        #pragma unroll
        for (int i = 0; i < 2; ++i) {
            int row = 16*(2*w+i) + row4;
            gl_lds16(ctxh + (size_t)(m0+row)*Dc + k0 + scol, (char*)As + (2*w+i)*1024);
            gl_lds16(Woh  + (size_t)(n0+row)*Dc + k0 + scol, (char*)Bh + (2*w+i)*1024);
            gl_lds16(Wol  + (size_t)(n0+row)*Dc + k0 + scol, (char*)Bl + (2*w+i)*1024);
        }
        WAIT_VM0; __syncthreads();
        bf16x8 a[4], bh[4], bl[4];
        const int s2 = lane >> 4;
        #pragma unroll
        for (int i = 0; i < 4; ++i) {
            int Ra = wm*64 + i*16 + (lane&15);
            int Rb = wn*64 + i*16 + (lane&15);
            a[i]  = *(const bf16x8*)((const char*)&As[Ra][0] + ((s2 ^ (Ra&3))*16));
            bh[i] = *(const bf16x8*)((const char*)&Bh[Rb][0] + ((s2 ^ (Rb&3))*16));
            bl[i] = *(const bf16x8*)((const char*)&Bl[Rb][0] + ((s2 ^ (Rb&3))*16));
        }
        #pragma unroll
        for (int mi = 0; mi < 4; ++mi)
            #pragma unroll
            for (int ni = 0; ni < 4; ++ni) {
                acc[mi][ni] = __builtin_amdgcn_mfma_f32_16x16x32_bf16(a[mi], bh[ni], acc[mi][ni], 0, 0, 0);
                acc[mi][ni] = __builtin_amdgcn_mfma_f32_16x16x32_bf16(a[mi], bl[ni], acc[mi][ni], 0, 0, 0);
            }
        __syncthreads();
    }
    #pragma unroll
    for (int mi = 0; mi < 4; ++mi)
        #pragma unroll
        for (int ni = 0; ni < 4; ++ni)
            #pragma unroll
            for (int r = 0; r < 4; ++r) {
                int row = m0 + wm*64 + mi*16 + (lane>>4)*4 + r;
                int col = n0 + wn*64 + ni*16 + (lane&15);
                out[(size_t)row * Dc + col] = acc[mi][ni][r] + bo[col];
            }
}

// ---------------------------------------------------------------------------
extern "C" void kernel_launch(void* const* d_in, const int* in_sizes, int n_in,
                              void* d_out, int out_size, void* d_ws, size_t ws_size,
                              hipStream_t stream)
{
    const float* hidden = (const float*)d_in[0];
    const float* pos    = (const float*)d_in[1];
    const float* Wcq = (const float*)d_in[2];  const float* bcq = (const float*)d_in[3];
    const float* Wck = (const float*)d_in[4];  const float* bck = (const float*)d_in[5];
    const float* Wpq = (const float*)d_in[6];  const float* bpq = (const float*)d_in[7];
    const float* Wpk = (const float*)d_in[8];  const float* bpk = (const float*)d_in[9];
    const float* relb = (const float*)d_in[10];
    const float* Wo  = (const float*)d_in[11]; const float* bo  = (const float*)d_in[12];

    float* out  = (float*)d_out;
    float* attn = out + (size_t)Mc * Dc;

    // ws (bf16 elems): Woh[0,1M) Wol[1M,2M) Wt[2M,6M) (ctxh overlays Wt)
    // Qc[6M,14M) Kc[14M,22M) VT[22M,26M)   -> 52 MB
    __bf16* ws   = (__bf16*)d_ws;
    __bf16* Woh  = ws;
    __bf16* Wol  = ws + (1u<<20);
    __bf16* Wt   = ws + (2u<<20);
    __bf16* ctxh = Wt;
    __bf16* Qc   = ws + (6u<<20);
    __bf16* Kc   = ws + (14u<<20);
    __bf16* VTb  = ws + (22u<<20);

    prep_kernel<<<dim3(16, 8, 5), 256, 0, stream>>>(Wcq, Wck, Wpq, Wpk, Wo, Wt, Woh, Wol);
    proj_kernel<<<dim3(1024), 256, 0, stream>>>(hidden, pos, Wt, bcq, bck, bpq, bpk, Qc, Kc);
    vt_kernel<<<dim3(Lc/128, 32), 256, 0, stream>>>(Kc, VTb);
    attn_kernel<<<dim3(512), 256, 0, stream>>>(Qc, Kc, VTb, relb, attn, ctxh);
    out_kernel<<<dim3(8, 32), 256, 0, stream>>>(ctxh, Woh, Wol, bo, out);
}